// Round 1
// baseline (61.860 us; speedup 1.0000x reference)
//
#include <hip/hip_runtime.h>
#include <math.h>

// Problem constants (reference: N=65536 rows, C=1000 classes)
#define CCOLS 1000
#define NF4   250          // CCOLS / 4 float4 chunks per row (exact)

// Kernel 1: one 64-lane wave per row. Computes per-row
//   m   = max(logits[row,:]), mi = argmax (first index on tie)
//   lse = m + log(sum(exp(x - m)))
//   tlogp = logits[row, tt] - lse            (tt = super_classes[target[row]])
//   w   = class_weights[tt, mi]
// and accumulates per-block (4 rows) partial (num, den) = (sum -w*tlogp, sum w)
// into partials[2*blockIdx.x + {0,1}].
__global__ __launch_bounds__(256) void cacel_rows_kernel(
    const float* __restrict__ logits,
    const float* __restrict__ cw,
    const int*   __restrict__ tgt,
    const int*   __restrict__ sc,
    float*       __restrict__ partials,
    int nrows)
{
    const int wid  = threadIdx.x >> 6;   // wave id within block (0..3)
    const int lane = threadIdx.x & 63;
    const int row  = blockIdx.x * 4 + wid;

    float num = 0.0f, den = 0.0f;

    if (row < nrows) {
        // super-class target for this row (uniform load, all lanes same addr)
        const int tt = sc[tgt[row]];

        const float4* rp = (const float4*)(logits + (size_t)row * CCOLS);

        // Load the whole row into registers: 4 float4 per lane, coalesced.
        float4 v[4];
#pragma unroll
        for (int it = 0; it < 4; ++it) {
            const int f = it * 64 + lane;
            if (f < NF4) {
                v[it] = rp[f];
            } else {
                v[it] = make_float4(-INFINITY, -INFINITY, -INFINITY, -INFINITY);
            }
        }

        // Pass 1 (registers): local max + argmax (first index on tie),
        // and capture the target-column logit.
        float m  = -INFINITY;
        int   mi = 0x7fffffff;
        float tval = 0.0f;   // exactly one lane in the wave sees column tt
#pragma unroll
        for (int it = 0; it < 4; ++it) {
            const int cbase = (it * 64 + lane) * 4;
            const float* pv = (const float*)&v[it];
#pragma unroll
            for (int j = 0; j < 4; ++j) {
                const float x = pv[j];
                const int   c = cbase + j;     // pad lanes have c >= 1000 != tt
                if (x > m) { m = x; mi = c; }
                if (c == tt) tval = x;
            }
        }

        // Wave reduce: max with min-index tie-break.
#pragma unroll
        for (int s = 32; s >= 1; s >>= 1) {
            const float om = __shfl_xor(m,  s, 64);
            const int   oi = __shfl_xor(mi, s, 64);
            if (om > m || (om == m && oi < mi)) { m = om; mi = oi; }
        }

        // Pass 2 (registers): sum exp(x - m). Pads give exp(-inf)=0.
        float ssum = 0.0f;
#pragma unroll
        for (int it = 0; it < 4; ++it) {
            const float* pv = (const float*)&v[it];
#pragma unroll
            for (int j = 0; j < 4; ++j) {
                ssum += __expf(pv[j] - m);
            }
        }
#pragma unroll
        for (int s = 32; s >= 1; s >>= 1) ssum += __shfl_xor(ssum, s, 64);

        // Broadcast the target logit (non-holders contribute 0).
#pragma unroll
        for (int s = 32; s >= 1; s >>= 1) tval += __shfl_xor(tval, s, 64);

        if (lane == 0) {
            const float lse   = m + __logf(ssum);
            const float tlogp = tval - lse;                    // logp[row, tt]
            const float w     = cw[(size_t)tt * CCOLS + mi];   // class_weights[tt, pred]
            num = -w * tlogp;
            den = w;
        }
    }

    // Block reduce: 4 wave-leaders -> one (num, den) pair per block.
    __shared__ float snum[4], sden[4];
    if (lane == 0) { snum[wid] = num; sden[wid] = den; }
    __syncthreads();
    if (threadIdx.x == 0) {
        partials[2 * (size_t)blockIdx.x + 0] = snum[0] + snum[1] + snum[2] + snum[3];
        partials[2 * (size_t)blockIdx.x + 1] = sden[0] + sden[1] + sden[2] + sden[3];
    }
}

// Kernel 2: deterministic single-block tree reduction of the partials,
// final scalar = sum(num) / sum(den).
__global__ __launch_bounds__(256) void cacel_final_kernel(
    const float* __restrict__ partials, int nblk, float* __restrict__ out)
{
    float n = 0.0f, d = 0.0f;
    for (int i = threadIdx.x; i < nblk; i += 256) {
        n += partials[2 * (size_t)i + 0];
        d += partials[2 * (size_t)i + 1];
    }
    __shared__ float sn[256], sd[256];
    sn[threadIdx.x] = n;
    sd[threadIdx.x] = d;
    __syncthreads();
    for (int s = 128; s > 0; s >>= 1) {
        if (threadIdx.x < s) {
            sn[threadIdx.x] += sn[threadIdx.x + s];
            sd[threadIdx.x] += sd[threadIdx.x + s];
        }
        __syncthreads();
    }
    if (threadIdx.x == 0) out[0] = sn[0] / sd[0];
}

extern "C" void kernel_launch(void* const* d_in, const int* in_sizes, int n_in,
                              void* d_out, int out_size, void* d_ws, size_t ws_size,
                              hipStream_t stream) {
    (void)n_in; (void)out_size; (void)ws_size;
    const float* logits = (const float*)d_in[0];   // [N, 1000] f32
    const float* cw     = (const float*)d_in[1];   // [1000, 1000] f32
    const int*   tgt    = (const int*)d_in[2];     // [N] i32
    const int*   sc     = (const int*)d_in[3];     // [1000] i32

    const int N    = in_sizes[2];
    const int nblk = (N + 3) / 4;                  // 4 rows (waves) per block

    float* partials = (float*)d_ws;                // nblk * 2 floats

    cacel_rows_kernel<<<nblk, 256, 0, stream>>>(logits, cw, tgt, sc, partials, N);
    cacel_final_kernel<<<1, 256, 0, stream>>>(partials, nblk, (float*)d_out);
}

// Round 2
// 56.659 us; speedup vs baseline: 1.0918x; 1.0918x over previous
//
#include <hip/hip_runtime.h>
#include <math.h>

// Problem: N=65536 rows, C=1000 classes, f32. Single-scalar output.
#define CCOLS 1000
#define NF4   250          // CCOLS/4 float4 chunks per row (exact)
#define RPW   8            // rows per wave (pipelined)
#define WPB   4            // waves per block (256 threads)

typedef float f32x4 __attribute__((ext_vector_type(4)));

__device__ __forceinline__ f32x4 ntload(const f32x4* p) {
    return __builtin_nontemporal_load(p);
}

// Load one 1000-float row into 4 f32x4 per lane (chunks lane, 64+lane, 128+lane, 192+lane).
__device__ __forceinline__ void loadrow(f32x4& b0, f32x4& b1, f32x4& b2, f32x4& b3,
                                        const float* __restrict__ logits, int row, int lane) {
    const f32x4* rp = (const f32x4*)(logits + (size_t)row * CCOLS);
    b0 = ntload(rp + lane);
    b1 = ntload(rp + 64 + lane);
    b2 = ntload(rp + 128 + lane);
    if (lane < NF4 - 192) {            // chunks 192..249 valid for lanes 0..57
        b3 = ntload(rp + 192 + lane);
    } else {
        const f32x4 ninf = {-INFINITY, -INFINITY, -INFINITY, -INFINITY};
        b3 = ninf;
    }
}

// Full per-row computation: max, argmax(first-index), lse, weighted loss accumulate.
__device__ __forceinline__ void process_row(f32x4 v0, f32x4 v1, f32x4 v2, f32x4 v3,
                                            int lane, int tt, float tval,
                                            const float* __restrict__ cw,
                                            float& num, float& den) {
    // local max (no index tracking — fmax chain, fusable to v_max3)
    float m = -INFINITY;
#pragma unroll
    for (int j = 0; j < 4; ++j) {
        m = fmaxf(m, v0[j]); m = fmaxf(m, v1[j]);
        m = fmaxf(m, v2[j]); m = fmaxf(m, v3[j]);
    }
    // wave max
#pragma unroll
    for (int s = 32; s >= 1; s >>= 1) m = fmaxf(m, __shfl_xor(m, s, 64));

    // exp-sum + first-index-of-max in one register pass
    float ssum = 0.0f;
    int   mi   = 0x7fffffff;
#pragma unroll
    for (int j = 0; j < 4; ++j) {
        { const float x = v0[j]; const int c = lane * 4 + j;
          ssum += __expf(x - m); if (x == m) mi = min(mi, c); }
        { const float x = v1[j]; const int c = (64 + lane) * 4 + j;
          ssum += __expf(x - m); if (x == m) mi = min(mi, c); }
        { const float x = v2[j]; const int c = (128 + lane) * 4 + j;
          ssum += __expf(x - m); if (x == m) mi = min(mi, c); }
        { const float x = v3[j]; const int c = (192 + lane) * 4 + j;
          ssum += __expf(x - m); if (x == m) mi = min(mi, c); }
    }
    // interleaved wave reduce: sum + min-index
#pragma unroll
    for (int s = 32; s >= 1; s >>= 1) {
        ssum += __shfl_xor(ssum, s, 64);
        mi = min(mi, __shfl_xor(mi, s, 64));
    }

    const float lse = m + __logf(ssum);
    // all lanes load the same cw entry (1 request, broadcast); L2-resident table
    const float w = cw[(size_t)tt * CCOLS + mi];
    num += w * (lse - tval);   // == -w * (tval - lse)
    den += w;
}

__global__ __launch_bounds__(256) void cacel_rows_kernel(
    const float* __restrict__ logits,
    const float* __restrict__ cw,
    const int*   __restrict__ tgt,
    const int*   __restrict__ sc,
    float*       __restrict__ partials,
    int nrows)
{
    const int wid  = threadIdx.x >> 6;
    const int lane = threadIdx.x & 63;
    const int W    = blockIdx.x * WPB + wid;
    const int r0   = __builtin_amdgcn_readfirstlane(W * RPW);  // wave-uniform -> SGPR

    // Hoisted dependent index chains for all RPW rows (scalar loads, issued in parallel):
    // tgt[row] -> sc[.] -> logits[row, tt]
    int   tts[RPW];
    float tvals[RPW];
#pragma unroll
    for (int k = 0; k < RPW; ++k) {
        const int row = r0 + k;
        tts[k] = (row < nrows) ? sc[tgt[row]] : 0;
    }
#pragma unroll
    for (int k = 0; k < RPW; ++k) {
        const int row = r0 + k;
        tvals[k] = (row < nrows) ? logits[(size_t)row * CCOLS + tts[k]] : 0.0f;
    }

    float num = 0.0f, den = 0.0f;

    // Double-buffered register pipeline over RPW rows.
    f32x4 a0, a1, a2, a3, b0, b1, b2, b3;
    if (r0 < nrows) loadrow(a0, a1, a2, a3, logits, r0, lane);

#pragma unroll
    for (int k = 0; k < RPW; ++k) {
        const int row = r0 + k;
        if (row < nrows) {
            if ((k & 1) == 0) {
                if (k + 1 < RPW && row + 1 < nrows)
                    loadrow(b0, b1, b2, b3, logits, row + 1, lane);   // prefetch next
                process_row(a0, a1, a2, a3, lane, tts[k], tvals[k], cw, num, den);
            } else {
                if (k + 1 < RPW && row + 1 < nrows)
                    loadrow(a0, a1, a2, a3, logits, row + 1, lane);
                process_row(b0, b1, b2, b3, lane, tts[k], tvals[k], cw, num, den);
            }
        }
    }

    // Block reduce: 4 wave partials -> 2 floats per block.
    __shared__ float snum[WPB], sden[WPB];
    if (lane == 0) { snum[wid] = num; sden[wid] = den; }
    __syncthreads();
    if (threadIdx.x == 0) {
        partials[2 * (size_t)blockIdx.x + 0] = snum[0] + snum[1] + snum[2] + snum[3];
        partials[2 * (size_t)blockIdx.x + 1] = sden[0] + sden[1] + sden[2] + sden[3];
    }
}

__global__ __launch_bounds__(256) void cacel_final_kernel(
    const float* __restrict__ partials, int nblk, float* __restrict__ out)
{
    float n = 0.0f, d = 0.0f;
    for (int i = threadIdx.x; i < nblk; i += 256) {
        n += partials[2 * (size_t)i + 0];
        d += partials[2 * (size_t)i + 1];
    }
    __shared__ float sn[256], sd[256];
    sn[threadIdx.x] = n;
    sd[threadIdx.x] = d;
    __syncthreads();
    for (int s = 128; s > 0; s >>= 1) {
        if (threadIdx.x < s) {
            sn[threadIdx.x] += sn[threadIdx.x + s];
            sd[threadIdx.x] += sd[threadIdx.x + s];
        }
        __syncthreads();
    }
    if (threadIdx.x == 0) out[0] = sn[0] / sd[0];
}

extern "C" void kernel_launch(void* const* d_in, const int* in_sizes, int n_in,
                              void* d_out, int out_size, void* d_ws, size_t ws_size,
                              hipStream_t stream) {
    (void)n_in; (void)out_size; (void)ws_size;
    const float* logits = (const float*)d_in[0];   // [N, 1000] f32
    const float* cw     = (const float*)d_in[1];   // [1000, 1000] f32
    const int*   tgt    = (const int*)d_in[2];     // [N] i32
    const int*   sc     = (const int*)d_in[3];     // [1000] i32

    const int N    = in_sizes[2];
    const int rows_per_block = WPB * RPW;                       // 32
    const int nblk = (N + rows_per_block - 1) / rows_per_block; // 2048 at N=65536

    float* partials = (float*)d_ws;   // nblk * 2 floats

    cacel_rows_kernel<<<nblk, 256, 0, stream>>>(logits, cw, tgt, sc, partials, N);
    cacel_final_kernel<<<1, 256, 0, stream>>>(partials, nblk, (float*)d_out);
}